// Round 7
// baseline (7214.487 us; speedup 1.0000x reference)
//
#include <hip/hip_runtime.h>
#include <cmath>

#define B_    8
#define LS_   512
#define L_    1024
#define D_    1024
#define H_    16
#define HD_   64
#define FF_   4096
#define NL_   12
#define NTOK_ (B_*L_)

typedef __attribute__((ext_vector_type(8))) short short8;
typedef __bf16 bf16x8 __attribute__((ext_vector_type(8)));
typedef __attribute__((ext_vector_type(4))) float f32x4;
typedef unsigned short u16;

__device__ __forceinline__ u16 f2bf(float f) {
  unsigned u = __builtin_bit_cast(unsigned, f);
  unsigned r = (u + 0x7fffu + ((u >> 16) & 1u)) >> 16;
  return (u16)r;
}

__device__ __forceinline__ void load_lds16(const void* g, void* l) {
  __builtin_amdgcn_global_load_lds(
      (const __attribute__((address_space(1))) unsigned*)g,
      (__attribute__((address_space(3))) unsigned*)l, 16, 0, 0);
}

// raw barrier: no compiler-inserted vmcnt(0) drain
__device__ __forceinline__ void raw_barrier() {
  __builtin_amdgcn_sched_barrier(0);
  __builtin_amdgcn_s_barrier();
  __builtin_amdgcn_sched_barrier(0);
}

__device__ __forceinline__ void lgkm0() {
  asm volatile("s_waitcnt lgkmcnt(0)" ::: "memory");
  __builtin_amdgcn_sched_barrier(0);
}

// ---------------- pos-embed + concat ----------------
__global__ void posadd_kernel(const float* __restrict__ sensor, const float* __restrict__ traj,
                              const float* __restrict__ pos, float* __restrict__ x) {
  int idx = blockIdx.x * blockDim.x + threadIdx.x;   // float4 index
  int d4 = idx & (D_/4 - 1);
  int n  = idx >> 8;            // D_/4 == 256
  int l  = n & (L_ - 1);
  int b  = n >> 10;             // L_ == 1024
  const float* src = (l < LS_) ? (sensor + ((size_t)(b*LS_ + l))*D_)
                               : (traj   + ((size_t)(b*LS_ + l - LS_))*D_);
  float4 v = reinterpret_cast<const float4*>(src)[d4];
  float4 p = reinterpret_cast<const float4*>(pos + (size_t)l*D_)[d4];
  v.x += p.x; v.y += p.y; v.z += p.z; v.w += p.w;
  reinterpret_cast<float4*>(x + (size_t)n*D_)[d4] = v;
}

// ---------------- LayerNorm ----------------
template<typename OUT>
__global__ __launch_bounds__(256) void ln_kernel(const float* __restrict__ x,
                                                 const float* __restrict__ gam,
                                                 const float* __restrict__ bet,
                                                 OUT* __restrict__ out) {
  int row = blockIdx.x;
  int t = threadIdx.x;
  float4 v = reinterpret_cast<const float4*>(x + (size_t)row * D_)[t];
  float sum = v.x + v.y + v.z + v.w;
  float sq  = v.x*v.x + v.y*v.y + v.z*v.z + v.w*v.w;
  #pragma unroll
  for (int o = 1; o < 64; o <<= 1) {
    sum += __shfl_xor(sum, o, 64);
    sq  += __shfl_xor(sq,  o, 64);
  }
  __shared__ float ps[4], pq[4];
  int w = t >> 6;
  if ((t & 63) == 0) { ps[w] = sum; pq[w] = sq; }
  __syncthreads();
  sum = ps[0] + ps[1] + ps[2] + ps[3];
  sq  = pq[0] + pq[1] + pq[2] + pq[3];
  float mean = sum * (1.0f / D_);
  float var  = sq  * (1.0f / D_) - mean * mean;
  float inv  = rsqrtf(var + 1e-5f);
  float4 g  = reinterpret_cast<const float4*>(gam)[t];
  float4 bb = reinterpret_cast<const float4*>(bet)[t];
  float o0 = (v.x - mean) * inv * g.x + bb.x;
  float o1 = (v.y - mean) * inv * g.y + bb.y;
  float o2 = (v.z - mean) * inv * g.z + bb.z;
  float o3 = (v.w - mean) * inv * g.w + bb.w;
  if constexpr (sizeof(OUT) == 2) {
    ushort4 r; r.x = f2bf(o0); r.y = f2bf(o1); r.z = f2bf(o2); r.w = f2bf(o3);
    reinterpret_cast<ushort4*>(out + (size_t)row * D_)[t] = r;
  } else {
    float4 r; r.x = o0; r.y = o1; r.z = o2; r.w = o3;
    reinterpret_cast<float4*>(out + (size_t)row * D_)[t] = r;
  }
}

// ---------------- fp32 -> bf16 cast ----------------
__global__ void cast_kernel(const float* __restrict__ in, u16* __restrict__ out, int n4) {
  int i = blockIdx.x * blockDim.x + threadIdx.x;
  if (i >= n4) return;
  float4 v = reinterpret_cast<const float4*>(in)[i];
  ushort4 r; r.x = f2bf(v.x); r.y = f2bf(v.y); r.z = f2bf(v.z); r.w = f2bf(v.w);
  reinterpret_cast<ushort4*>(out)[i] = r;
}

// ================= 256x256 8-phase GEMM (T2+T3+T4+T5) =================
// C[n,m] = A[n,:]·W[m,:] + bias.  512 thr = 8 waves (2 M x 4 N), BK=64.
// LDS: 2 buf x (A 32KB + B 32KB) = 128KB. st_16x32 swizzle: u16 column index
// kc is XORed with ((row>>2)&1)<<4; implemented as inverse-swizzled GLOBAL
// source (linear gload_lds dest) + swizzled ds_read (rule #21).
// EPI 1: gelu->bf16 nt-store; EPI 3: QKV routing.
#define LDIDX(rowG, kc16) ((rowG)*64 + ((kc16) ^ ((((rowG)>>2)&1)<<4)))

template<int EPI>
__global__ __launch_bounds__(512) void gemm8_kernel(const u16* __restrict__ A, const u16* __restrict__ W,
                                                    const float* __restrict__ bias, u16* __restrict__ Cbf,
                                                    u16* __restrict__ Kt, u16* __restrict__ Vt,
                                                    int M, int K, int gx) {
  __shared__ u16 lsA8[2][16384];
  __shared__ u16 lsB8[2][16384];
  int tid = threadIdx.x;
  int lane = tid & 63;
  int w = tid >> 6;                 // 0..7
  int wr = w >> 2, wc = w & 3;      // 2 x 4 wave grid
  int bid = blockIdx.x;             // x-major: consecutive = row tiles, shared W panel
  int bx = bid % gx, by = bid / gx;
  int row0 = bx << 8;
  int col0 = by << 8;
  int l15 = lane & 15;
  int l4  = lane >> 4;

  // staging: 32 chunks of 1024B per 256x64 tile; wave w owns chunks 4w..4w+3.
  // source: natural row, k-column XORed by 16 u16 for lanes>=32 (involution).
  const u16* srcA[4]; const u16* srcB[4];
  u16* dstA[2][4]; u16* dstB[2][4];
  int kcs = ((lane & 7) << 3) ^ ((lane >= 32) ? 16 : 0);
  #pragma unroll
  for (int j = 0; j < 4; j++) {
    int c = 4*w + j;
    int rr = c*8 + (lane >> 3);
    srcA[j] = A + (size_t)(row0 + rr) * K + kcs;
    srcB[j] = W + (size_t)(col0 + rr) * K + kcs;
    dstA[0][j] = &lsA8[0][c*512]; dstA[1][j] = &lsA8[1][c*512];
    dstB[0][j] = &lsB8[0][c*512]; dstB[1][j] = &lsB8[1][c*512];
  }

  f32x4 acc[8][4] = {};
  int nt = K >> 6;

  // prologue: stage K-tile 0 into buf 0
  #pragma unroll
  for (int j = 0; j < 4; j++) load_lds16(srcA[j], dstA[0][j]);
  #pragma unroll
  for (int j = 0; j < 4; j++) load_lds16(srcB[j], dstB[0][j]);
  asm volatile("s_waitcnt vmcnt(0)" ::: "memory");
  raw_barrier();

  for (int t = 0; t < nt; t++) {
    int cur = t & 1, nb = cur ^ 1;
    bool pf = (t + 1 < nt);
    int koff = (t + 1) << 6;
    bf16x8 af[4][2], bf[2][2], bf2[2][2];
    // ---- ph0: A-rows 0-3 + B-cols 0-1 frags; issue A(t+1) ----
    #pragma unroll
    for (int i = 0; i < 4; i++)
      #pragma unroll
      for (int ks = 0; ks < 2; ks++)
        af[i][ks] = *reinterpret_cast<const bf16x8*>(&lsA8[cur][LDIDX(wr*128 + i*16 + l15, ks*32 + l4*8)]);
    #pragma unroll
    for (int i = 0; i < 2; i++)
      #pragma unroll
      for (int ks = 0; ks < 2; ks++)
        bf[i][ks] = *reinterpret_cast<const bf16x8*>(&lsB8[cur][LDIDX(wc*64 + i*16 + l15, ks*32 + l4*8)]);
    if (pf) {
      #pragma unroll
      for (int j = 0; j < 4; j++) load_lds16(srcA[j] + koff, dstA[nb][j]);
    }
    raw_barrier();
    lgkm0();
    __builtin_amdgcn_s_setprio(1);
    #pragma unroll
    for (int i = 0; i < 4; i++)
      #pragma unroll
      for (int c = 0; c < 2; c++)
        #pragma unroll
        for (int ks = 0; ks < 2; ks++)
          acc[i][c] = __builtin_amdgcn_mfma_f32_16x16x32_bf16(af[i][ks], bf[c][ks], acc[i][c], 0, 0, 0);
    __builtin_amdgcn_s_setprio(0);
    raw_barrier();
    // ---- ph1: B-cols 2-3 frags; issue B(t+1) ----
    #pragma unroll
    for (int i = 0; i < 2; i++)
      #pragma unroll
      for (int ks = 0; ks < 2; ks++)
        bf2[i][ks] = *reinterpret_cast<const bf16x8*>(&lsB8[cur][LDIDX(wc*64 + (i+2)*16 + l15, ks*32 + l4*8)]);
    if (pf) {
      #pragma unroll
      for (int j = 0; j < 4; j++) load_lds16(srcB[j] + koff, dstB[nb][j]);
    }
    raw_barrier();
    lgkm0();
    __builtin_amdgcn_s_setprio(1);
    #pragma unroll
    for (int i = 0; i < 4; i++)
      #pragma unroll
      for (int c = 0; c < 2; c++)
        #pragma unroll
        for (int ks = 0; ks < 2; ks++)
          acc[i][c+2] = __builtin_amdgcn_mfma_f32_16x16x32_bf16(af[i][ks], bf2[c][ks], acc[i][c+2], 0, 0, 0);
    __builtin_amdgcn_s_setprio(0);
    raw_barrier();
    // ---- ph2: A-rows 4-7 frags (reuse af regs) ----
    #pragma unroll
    for (int i = 0; i < 4; i++)
      #pragma unroll
      for (int ks = 0; ks < 2; ks++)
        af[i][ks] = *reinterpret_cast<const bf16x8*>(&lsA8[cur][LDIDX(wr*128 + (i+4)*16 + l15, ks*32 + l4*8)]);
    raw_barrier();
    lgkm0();
    __builtin_amdgcn_s_setprio(1);
    #pragma unroll
    for (int i = 0; i < 4; i++)
      #pragma unroll
      for (int c = 0; c < 2; c++)
        #pragma unroll
        for (int ks = 0; ks < 2; ks++)
          acc[i+4][c] = __builtin_amdgcn_mfma_f32_16x16x32_bf16(af[i][ks], bf[c][ks], acc[i+4][c], 0, 0, 0);
    __builtin_amdgcn_s_setprio(0);
    raw_barrier();
    // ---- ph3: remaining quadrant; drain t+1's loads ----
    __builtin_amdgcn_s_setprio(1);
    #pragma unroll
    for (int i = 0; i < 4; i++)
      #pragma unroll
      for (int c = 0; c < 2; c++)
        #pragma unroll
        for (int ks = 0; ks < 2; ks++)
          acc[i+4][c+2] = __builtin_amdgcn_mfma_f32_16x16x32_bf16(af[i][ks], bf2[c][ks], acc[i+4][c+2], 0, 0, 0);
    __builtin_amdgcn_s_setprio(0);
    if (pf) asm volatile("s_waitcnt vmcnt(0)" ::: "memory");
    raw_barrier();
  }

  // epilogue
  #pragma unroll
  for (int fc = 0; fc < 4; fc++) {
    int col = col0 + wc*64 + fc*16 + l15;
    float bv = bias[col];
    #pragma unroll
    for (int fr = 0; fr < 8; fr++) {
      #pragma unroll
      for (int r = 0; r < 4; r++) {
        int row = row0 + wr*128 + fr*16 + l4*4 + r;
        float v = acc[fr][fc][r] + bv;
        if constexpr (EPI == 1) {
          float gl = 0.5f * v * (1.0f + erff(v * 0.70710678118f));
          __builtin_nontemporal_store(f2bf(gl), &Cbf[(size_t)row * M + col]);
        } else {
          int bb = row >> 10, ll = row & 1023;
          int tile = ll >> 6, kv = ll & 63;
          if (col0 < 1024) {
            __builtin_nontemporal_store(f2bf(v), &Cbf[(size_t)row * 1024 + col]);
          } else if (col0 < 2048) {
            int cc = col - 1024;
            int hh = cc >> 6, d = cc & 63;
            size_t base = (((size_t)(bb*16 + hh)*16 + tile) << 12);
            __builtin_nontemporal_store(f2bf(v), &Kt[base + kv*64 + (d ^ ((kv & 7) << 3))]);
          } else {
            int cc = col - 2048;
            int hh = cc >> 6, d = cc & 63;
            int pos = ((kv & 15) << 2) | (((kv >> 5) & 1) << 1) | ((kv >> 4) & 1);
            size_t base = (((size_t)(bb*16 + hh)*16 + tile) << 12);
            __builtin_nontemporal_store(f2bf(v), &Vt[base + d*64 + (pos ^ ((d & 7) << 3))]);
          }
        }
      }
    }
  }
}

// ---------------- 128x128 MFMA GEMM (proj / FFN2), EPI2 residual ----------------
template<int EPI>
__global__ __launch_bounds__(256) void gemm_kernel(const u16* __restrict__ A, const u16* __restrict__ W,
                                                   const float* __restrict__ bias, u16* __restrict__ Cbf,
                                                   float* __restrict__ resid,
                                                   int M, int K, int gx) {
  __shared__ u16 lsA[3][4096];
  __shared__ u16 lsB[3][4096];
  int tid = threadIdx.x;
  int lane = tid & 63;
  int w = tid >> 6;
  int wg = blockIdx.x;
  int bx = wg % gx, by = wg / gx;
  int row0 = bx << 7;
  int col0 = by << 7;
  int wr = w >> 1, wc = w & 1;

  const u16* pA[2]; const u16* pB[2];
  int dstc[2];
  #pragma unroll
  for (int i = 0; i < 2; i++) {
    int c = w * 2 + i;
    int rt = c * 16 + (lane >> 2);
    int g  = (lane & 3) ^ ((rt >> 1) & 3);
    pA[i] = A + (size_t)(row0 + rt) * K + g * 8;
    pB[i] = W + (size_t)(col0 + rt) * K + g * 8;
    dstc[i] = c * 512;
  }

  f32x4 acc[4][4] = {};
  int nt = K >> 5;

  #pragma unroll
  for (int i = 0; i < 2; i++) {
    load_lds16(pA[i], &lsA[0][dstc[i]]);
    load_lds16(pB[i], &lsB[0][dstc[i]]);
  }
  #pragma unroll
  for (int i = 0; i < 2; i++) {
    load_lds16(pA[i] + 32, &lsA[1][dstc[i]]);
    load_lds16(pB[i] + 32, &lsB[1][dstc[i]]);
  }
  asm volatile("s_waitcnt vmcnt(4)" ::: "memory");
  raw_barrier();

  int cur = 0;
  for (int t = 0; t < nt; t++) {
    int ib = (cur == 0) ? 2 : cur - 1;
    if (t + 2 < nt) {
      int kq = (t + 2) << 5;
      #pragma unroll
      for (int i = 0; i < 2; i++) {
        load_lds16(pA[i] + kq, &lsA[ib][dstc[i]]);
        load_lds16(pB[i] + kq, &lsB[ib][dstc[i]]);
      }
    }
    bf16x8 af[4], bfr[4];
    #pragma unroll
    for (int m = 0; m < 4; m++) {
      int row = wr * 64 + m * 16 + (lane & 15);
      int blk = (lane >> 4) ^ ((row >> 1) & 3);
      af[m] = *reinterpret_cast<const bf16x8*>(&lsA[cur][row * 32 + blk * 8]);
    }
    #pragma unroll
    for (int n = 0; n < 4; n++) {
      int row = wc * 64 + n * 16 + (lane & 15);
      int blk = (lane >> 4) ^ ((row >> 1) & 3);
      bfr[n] = *reinterpret_cast<const bf16x8*>(&lsB[cur][row * 32 + blk * 8]);
    }
    __builtin_amdgcn_s_setprio(1);
    #pragma unroll
    for (int m = 0; m < 4; m++)
      #pragma unroll
      for (int n = 0; n < 4; n++)
        acc[m][n] = __builtin_amdgcn_mfma_f32_16x16x32_bf16(af[m], bfr[n], acc[m][n], 0, 0, 0);
    __builtin_amdgcn_s_setprio(0);
    if (t + 2 < nt) {
      asm volatile("s_waitcnt vmcnt(4)" ::: "memory");
    } else {
      asm volatile("s_waitcnt vmcnt(0)" ::: "memory");
    }
    raw_barrier();
    cur = (cur == 2) ? 0 : cur + 1;
  }

  int rb = row0 + wr*64 + ((lane >> 4) << 2);
  int cb = col0 + wc*64 + (lane & 15);
  #pragma unroll
  for (int m = 0; m < 4; m++) {
    #pragma unroll
    for (int n = 0; n < 4; n++) {
      int col = cb + n * 16;
      float bv = bias[col];
      #pragma unroll
      for (int r = 0; r < 4; r++) {
        int row = rb + m * 16 + r;
        float v = acc[m][n][r] + bv;
        if constexpr (EPI == 0) {
          __builtin_nontemporal_store(f2bf(v), &Cbf[(size_t)row * M + col]);
        } else {
          float* p = &resid[(size_t)row * M + col];
          __builtin_nontemporal_store(*p + v, p);
        }
      }
    }
  }
}

// ---------------- flash attention, prefix-causal ----------------
__global__ __launch_bounds__(256) void attn_kernel(const u16* __restrict__ Qb,
                                                   const u16* __restrict__ Kt,
                                                   const u16* __restrict__ Vt,
                                                   u16* __restrict__ o) {
  __shared__ u16 KV[2][2][4096];
  __shared__ unsigned Ps[4][512];
  int tid = threadIdx.x;
  int lane = tid & 63;
  int wq = tid >> 6;
  int tile = blockIdx.x & 15;
  int bh = blockIdx.x >> 4;
  int b = bh >> 4;
  int h = bh & 15;
  int q0b = tile << 6;
  int q0 = q0b + wq * 16;
  size_t tok0 = (size_t)b * L_;
  int l15 = lane & 15;
  int l4  = lane >> 4;

  bf16x8 aq[2];
  #pragma unroll
  for (int kk = 0; kk < 2; kk++)
    aq[kk] = *reinterpret_cast<const bf16x8*>(Qb + (tok0 + q0 + l15) * 1024 + h * 64 + kk * 32 + (l4 << 3));

  f32x4 acc[4] = {};
  float mrow[4] = {-INFINITY, -INFINITY, -INFINITY, -INFINITY};
  float lrow[4] = {0.f, 0.f, 0.f, 0.f};
  int nkv_w = (q0b >= LS_) ? (q0 + 16) : LS_;
  bool causal = (q0b >= LS_);
  int ntiles = (q0b >= LS_) ? (tile + 1) : (LS_ >> 6);

  const u16* Kbh = Kt + (((size_t)bh) << 16);
  const u16* Vbh = Vt + (((size_t)bh) << 16);

  int soff = wq * 1024 + lane * 8;
  int doff = wq * 1024;

  #pragma unroll
  for (int i = 0; i < 2; i++) {
    load_lds16(Kbh + soff + i*512, &KV[0][0][doff + i*512]);
    load_lds16(Vbh + soff + i*512, &KV[0][1][doff + i*512]);
  }
  asm volatile("s_waitcnt vmcnt(0)" ::: "memory");
  raw_barrier();

  for (int t = 0; t < ntiles; t++) {
    int cur = t & 1;
    if (t + 1 < ntiles) {
      const u16* kn = Kbh + ((size_t)(t+1) << 12);
      const u16* vn = Vbh + ((size_t)(t+1) << 12);
      #pragma unroll
      for (int i = 0; i < 2; i++) {
        load_lds16(kn + soff + i*512, &KV[cur^1][0][doff + i*512]);
        load_lds16(vn + soff + i*512, &KV[cur^1][1][doff + i*512]);
      }
    }
    int kv0 = t << 6;
    if (kv0 < nkv_w) {
      const u16* Kl = &KV[cur][0][0];
      const u16* Vl = &KV[cur][1][0];
      f32x4 sf[4];
      __builtin_amdgcn_s_setprio(1);
      #pragma unroll
      for (int t4 = 0; t4 < 4; t4++) {
        f32x4 s = {0.f, 0.f, 0.f, 0.f};
        int kvl = t4*16 + l15;
        #pragma unroll
        for (int kk = 0; kk < 2; kk++) {
          bf16x8 bk = *reinterpret_cast<const bf16x8*>(&Kl[kvl*64 + ((kk*32 + l4*8) ^ ((l15 & 7) << 3))]);
          s = __builtin_amdgcn_mfma_f32_16x16x32_bf16(aq[kk], bk, s, 0, 0, 0);
        }
        sf[t4] = s * 0.125f;
      }
      __builtin_amdgcn_s_setprio(0);
      if (causal && (kv0 + 63 > q0)) {
        #pragma unroll
        for (int t4 = 0; t4 < 4; t4++) {
          int kvg = kv0 + t4*16 + l15;
          #pragma unroll
          for (int r = 0; r < 4; r++) {
            int qg = q0 + (l4 << 2) + r;
            if (kvg > qg) sf[t4][r] = -INFINITY;
          }
        }
      }
      float pv[4][4];
      #pragma unroll
      for (int r = 0; r < 4; r++) {
        float mx = fmaxf(fmaxf(sf[0][r], sf[1][r]), fmaxf(sf[2][r], sf[3][r]));
        #pragma unroll
        for (int off = 1; off < 16; off <<= 1) mx = fmaxf(mx, __shfl_xor(mx, off, 64));
        float mnew = fmaxf(mrow[r], mx);
        float alpha = __expf(mrow[r] - mnew);
        mrow[r] = mnew;
        float psum = 0.f;
        #pragma unroll
        for (int t4 = 0; t4 < 4; t4++) {
          float p = __expf(sf[t4][r] - mnew);
          pv[t4][r] = p;
          psum += p;
        }
        #pragma unroll
        for (int off = 1; off < 16; off <<= 1) psum += __shfl_xor(psum, off, 64);
        lrow[r] = lrow[r] * alpha + psum;
        #pragma unroll
        for (int h4 = 0; h4 < 4; h4++) acc[h4][r] *= alpha;
      }
      #pragma unroll
      for (int r = 0; r < 4; r++) {
        int ql = l4*4 + r;
        unsigned wA = (unsigned)f2bf(pv[0][r]) | ((unsigned)f2bf(pv[1][r]) << 16);
        unsigned wB = (unsigned)f2bf(pv[2][r]) | ((unsigned)f2bf(pv[3][r]) << 16);
        int xo = (ql & 7) << 2;
        Ps[wq][ql*32 + ((2*l15)     ^ xo)] = wA;
        Ps[wq][ql*32 + ((2*l15 + 1) ^ xo)] = wB;
      }
      __builtin_amdgcn_s_setprio(1);
      #pragma unroll
      for (int h4 = 0; h4 < 4; h4++) {
        int dl = h4*16 + l15;
        #pragma unroll
        for (int kk = 0; kk < 2; kk++) {
          bf16x8 pa = *reinterpret_cast<const bf16x8*>(
              (const u16*)&Ps[wq][0] + l15*64 + ((kk*32 + l4*8) ^ ((l15 & 7) << 3)));
          bf16x8 vb = *reinterpret_cast<const bf16x8*>(&Vl[dl*64 + ((kk*32 + l4*8) ^ ((l15 & 7) << 3))]);
          acc[h4] = __builtin_amdgcn_mfma_f32_16x16x32_bf16(pa, vb, acc[h4], 0, 0, 0);
        }
      }
      __builtin_amdgcn_s_setprio(0);
    }
    asm volatile("s_waitcnt vmcnt(0)" ::: "memory");
    raw_barrier();
  }
  #pragma unroll
  for (int h4 = 0; h4 < 4; h4++) {
    #pragma unroll
    for (int r = 0; r < 4; r++) {
      int row = q0 + (l4 << 2) + r;
      float ov = acc[h4][r] / lrow[r];
      o[(tok0 + row) * 1024 + h * 64 + h4*16 + l15] = f2bf(ov);
    }
  }
}

extern "C" void kernel_launch(void* const* d_in, const int* in_sizes, int n_in,
                              void* d_out, int out_size, void* d_ws, size_t ws_size,
                              hipStream_t stream) {
  (void)in_sizes; (void)n_in; (void)out_size; (void)ws_size;
  const float* sensor = (const float*)d_in[0];
  const float* traj   = (const float*)d_in[1];
  const float* pos    = (const float*)d_in[2];
  const float* ln1_s  = (const float*)d_in[3];
  const float* ln1_b  = (const float*)d_in[4];
  const float* qkv_w  = (const float*)d_in[5];
  const float* qkv_b  = (const float*)d_in[6];
  const float* out_w  = (const float*)d_in[7];
  const float* out_b  = (const float*)d_in[8];
  const float* ln2_s  = (const float*)d_in[9];
  const float* ln2_b  = (const float*)d_in[10];
  const float* w1     = (const float*)d_in[11];
  const float* b1     = (const float*)d_in[12];
  const float* w2     = (const float*)d_in[13];
  const float* b2     = (const float*)d_in[14];
  const float* fln_s  = (const float*)d_in[15];
  const float* fln_b  = (const float*)d_in[16];

  char* ws = (char*)d_ws;
  size_t off = 0;
  float* x  = (float*)(ws + off); off += (size_t)NTOK_ * D_ * 4;
  u16* h    = (u16*)(ws + off);   off += (size_t)NTOK_ * D_ * 2;
  u16* Qb   = (u16*)(ws + off);   off += (size_t)NTOK_ * D_ * 2;
  u16* Ktl  = (u16*)(ws + off);   off += (size_t)NTOK_ * D_ * 2;
  u16* Vtl  = (u16*)(ws + off);   off += (size_t)NTOK_ * D_ * 2;
  u16* ob   = (u16*)(ws + off);   off += (size_t)NTOK_ * D_ * 2;
  u16* ub   = (u16*)(ws + off);   off += (size_t)NTOK_ * FF_ * 2;
  u16* wb   = (u16*)(ws + off);   off += (size_t)FF_ * D_ * 2;

  posadd_kernel<<<NTOK_ * D_ / 1024, 256, 0, stream>>>(sensor, traj, pos, x);

  for (int i = 0; i < NL_; i++) {
    ln_kernel<u16><<<NTOK_, 256, 0, stream>>>(x, ln1_s + i*D_, ln1_b + i*D_, h);
    cast_kernel<<<(3*D_*D_/4)/256, 256, 0, stream>>>(qkv_w + (size_t)i*3*D_*D_, wb, 3*D_*D_/4);
    gemm8_kernel<3><<<32*12, 512, 0, stream>>>(h, wb, qkv_b + (size_t)i*3*D_, Qb, Ktl, Vtl, 3*D_, D_, 32);
    attn_kernel<<<B_*H_*(L_/64), 256, 0, stream>>>(Qb, Ktl, Vtl, ob);
    cast_kernel<<<(D_*D_/4)/256, 256, 0, stream>>>(out_w + (size_t)i*D_*D_, wb, D_*D_/4);
    gemm_kernel<2><<<64*8, 256, 0, stream>>>(ob, wb, out_b + (size_t)i*D_, nullptr, x, D_, D_, 64);
    ln_kernel<u16><<<NTOK_, 256, 0, stream>>>(x, ln2_s + i*D_, ln2_b + i*D_, h);
    cast_kernel<<<(FF_*D_/4)/256, 256, 0, stream>>>(w1 + (size_t)i*FF_*D_, wb, FF_*D_/4);
    gemm8_kernel<1><<<32*16, 512, 0, stream>>>(h, wb, b1 + (size_t)i*FF_, ub, nullptr, nullptr, FF_, D_, 32);
    cast_kernel<<<(FF_*D_/4)/256, 256, 0, stream>>>(w2 + (size_t)i*D_*FF_, wb, D_*FF_/4);
    gemm_kernel<2><<<64*8, 256, 0, stream>>>(ub, wb, b2 + (size_t)i*D_, nullptr, x, D_, FF_, 64);
  }
  ln_kernel<float><<<NTOK_, 256, 0, stream>>>(x, fln_s, fln_b, (float*)d_out);
}

// Round 8
// 7091.565 us; speedup vs baseline: 1.0173x; 1.0173x over previous
//
#include <hip/hip_runtime.h>
#include <cmath>

#define B_    8
#define LS_   512
#define L_    1024
#define D_    1024
#define H_    16
#define HD_   64
#define FF_   4096
#define NL_   12
#define NTOK_ (B_*L_)

typedef __attribute__((ext_vector_type(8))) short short8;
typedef __bf16 bf16x8 __attribute__((ext_vector_type(8)));
typedef __attribute__((ext_vector_type(4))) float f32x4;
typedef unsigned short u16;

__device__ __forceinline__ u16 f2bf(float f) {
  unsigned u = __builtin_bit_cast(unsigned, f);
  unsigned r = (u + 0x7fffu + ((u >> 16) & 1u)) >> 16;
  return (u16)r;
}

__device__ __forceinline__ void load_lds16(const void* g, void* l) {
  __builtin_amdgcn_global_load_lds(
      (const __attribute__((address_space(1))) unsigned*)g,
      (__attribute__((address_space(3))) unsigned*)l, 16, 0, 0);
}

// raw barrier: no compiler-inserted vmcnt(0) drain
__device__ __forceinline__ void raw_barrier() {
  __builtin_amdgcn_sched_barrier(0);
  __builtin_amdgcn_s_barrier();
  __builtin_amdgcn_sched_barrier(0);
}

// ---------------- pos-embed + concat ----------------
__global__ void posadd_kernel(const float* __restrict__ sensor, const float* __restrict__ traj,
                              const float* __restrict__ pos, float* __restrict__ x) {
  int idx = blockIdx.x * blockDim.x + threadIdx.x;   // float4 index
  int d4 = idx & (D_/4 - 1);
  int n  = idx >> 8;            // D_/4 == 256
  int l  = n & (L_ - 1);
  int b  = n >> 10;             // L_ == 1024
  const float* src = (l < LS_) ? (sensor + ((size_t)(b*LS_ + l))*D_)
                               : (traj   + ((size_t)(b*LS_ + l - LS_))*D_);
  float4 v = reinterpret_cast<const float4*>(src)[d4];
  float4 p = reinterpret_cast<const float4*>(pos + (size_t)l*D_)[d4];
  v.x += p.x; v.y += p.y; v.z += p.z; v.w += p.w;
  reinterpret_cast<float4*>(x + (size_t)n*D_)[d4] = v;
}

// ---------------- LayerNorm ----------------
template<typename OUT>
__global__ __launch_bounds__(256) void ln_kernel(const float* __restrict__ x,
                                                 const float* __restrict__ gam,
                                                 const float* __restrict__ bet,
                                                 OUT* __restrict__ out) {
  int row = blockIdx.x;
  int t = threadIdx.x;
  float4 v = reinterpret_cast<const float4*>(x + (size_t)row * D_)[t];
  float sum = v.x + v.y + v.z + v.w;
  float sq  = v.x*v.x + v.y*v.y + v.z*v.z + v.w*v.w;
  #pragma unroll
  for (int o = 1; o < 64; o <<= 1) {
    sum += __shfl_xor(sum, o, 64);
    sq  += __shfl_xor(sq,  o, 64);
  }
  __shared__ float ps[4], pq[4];
  int w = t >> 6;
  if ((t & 63) == 0) { ps[w] = sum; pq[w] = sq; }
  __syncthreads();
  sum = ps[0] + ps[1] + ps[2] + ps[3];
  sq  = pq[0] + pq[1] + pq[2] + pq[3];
  float mean = sum * (1.0f / D_);
  float var  = sq  * (1.0f / D_) - mean * mean;
  float inv  = rsqrtf(var + 1e-5f);
  float4 g  = reinterpret_cast<const float4*>(gam)[t];
  float4 bb = reinterpret_cast<const float4*>(bet)[t];
  float o0 = (v.x - mean) * inv * g.x + bb.x;
  float o1 = (v.y - mean) * inv * g.y + bb.y;
  float o2 = (v.z - mean) * inv * g.z + bb.z;
  float o3 = (v.w - mean) * inv * g.w + bb.w;
  if constexpr (sizeof(OUT) == 2) {
    ushort4 r; r.x = f2bf(o0); r.y = f2bf(o1); r.z = f2bf(o2); r.w = f2bf(o3);
    reinterpret_cast<ushort4*>(out + (size_t)row * D_)[t] = r;
  } else {
    float4 r; r.x = o0; r.y = o1; r.z = o2; r.w = o3;
    reinterpret_cast<float4*>(out + (size_t)row * D_)[t] = r;
  }
}

// ---------------- fp32 -> bf16 cast ----------------
__global__ void cast_kernel(const float* __restrict__ in, u16* __restrict__ out, int n4) {
  int i = blockIdx.x * blockDim.x + threadIdx.x;
  if (i >= n4) return;
  float4 v = reinterpret_cast<const float4*>(in)[i];
  ushort4 r; r.x = f2bf(v.x); r.y = f2bf(v.y); r.z = f2bf(v.z); r.w = f2bf(v.w);
  reinterpret_cast<ushort4*>(out)[i] = r;
}

// ============ 256x256 GEMM, half-K-tile 4-deep counted-vmcnt pipeline ============
// C[n,m] = A[n,:]·W[m,:] + bias.  512 thr = 8 waves (2M x 4N).  BK=64 as 2 halves.
// Per operand: 4 half-buffers [256 rows][32 u16] (64B rows), 16B-block swizzle
// blk ^= (row>>1)&3 (zero-conflict, proven in the 128^2 kernel), inverse applied
// on the global source so gload_lds dest stays linear.
// Phase (one per half): issue half(t+1,ks) -> vmcnt(8) -> barrier -> 12 ds_read
// -> 32 MFMA. Steady state keeps 8 loads in flight across barriers.
// EPI 1: gelu->bf16 nt-store; EPI 3: QKV routing.
template<int EPI>
__global__ __launch_bounds__(512) void gemm8_kernel(const u16* __restrict__ A, const u16* __restrict__ W,
                                                    const float* __restrict__ bias, u16* __restrict__ Cbf,
                                                    u16* __restrict__ Kt, u16* __restrict__ Vt,
                                                    int M, int K, int gx) {
  __shared__ u16 lsA8[4 * 8192];
  __shared__ u16 lsB8[4 * 8192];
  int tid = threadIdx.x;
  int lane = tid & 63;
  int w = tid >> 6;                 // 0..7
  int wr = w >> 2, wc = w & 3;      // 2 x 4 wave grid
  int bid = blockIdx.x;             // x-major: consecutive = row tiles, shared W panel
  int bx = bid % gx, by = bid / gx;
  int row0 = bx << 8;
  int col0 = by << 8;
  int l15 = lane & 15;
  int l4  = lane >> 4;

  // staging: per wave, 2 chunks of 1KB per operand-half. chunk c = w*2+j covers
  // rows c*16..c*16+15, 32 u16/row. lane -> (row_in=lane>>2, blk=lane&3);
  // source block = blk ^ ((row>>1)&3)  (inverse swizzle).
  const u16 *srcA[2], *srcB[2];
  u16 *dstA[2], *dstB[2];
  #pragma unroll
  for (int j = 0; j < 2; j++) {
    int c = w*2 + j;
    int r = c*16 + (lane >> 2);
    int blk = (lane & 3) ^ ((r >> 1) & 3);
    srcA[j] = A + (size_t)(row0 + r) * K + blk * 8;
    srcB[j] = W + (size_t)(col0 + r) * K + blk * 8;
    dstA[j] = &lsA8[c * 512];
    dstB[j] = &lsB8[c * 512];
  }

#define STAGE8(kt, ks, hb) do { \
    int _ko = (kt)*64 + (ks)*32; int _hо = (hb)*8192; \
    load_lds16(srcA[0] + _ko, dstA[0] + _hо); \
    load_lds16(srcA[1] + _ko, dstA[1] + _hо); \
    load_lds16(srcB[0] + _ko, dstB[0] + _hо); \
    load_lds16(srcB[1] + _ko, dstB[1] + _hо); \
  } while (0)

  // fragment read offsets (within a half-buffer)
  int rsw = (l15 >> 1) & 3;
  int aoff = (wr*128 + l15) * 32 + ((l4 ^ rsw) << 3);   // + i*512
  int boff = (wc*64  + l15) * 32 + ((l4 ^ rsw) << 3);   // + c*512

  f32x4 acc[8][4] = {};
  int nt = K >> 6;

  // prologue: both halves of K-tile 0 in flight
  STAGE8(0, 0, 0);
  STAGE8(0, 1, 1);

  for (int t = 0; t < nt; t++) {
    bool pf = (t + 1 < nt);
    #pragma unroll
    for (int ks = 0; ks < 2; ks++) {
      int n = t*2 + ks;
      int hb = n & 3;
      if (pf) {
        STAGE8(t+1, ks, (n+2) & 3);
        asm volatile("s_waitcnt vmcnt(8)" ::: "memory");
      } else if (ks == 0) {
        asm volatile("s_waitcnt vmcnt(4)" ::: "memory");
      } else {
        asm volatile("s_waitcnt vmcnt(0)" ::: "memory");
      }
      raw_barrier();
      bf16x8 af[8], bf[4];
      #pragma unroll
      for (int i = 0; i < 8; i++)
        af[i] = *reinterpret_cast<const bf16x8*>(&lsA8[hb*8192 + aoff + i*512]);
      #pragma unroll
      for (int c = 0; c < 4; c++)
        bf[c] = *reinterpret_cast<const bf16x8*>(&lsB8[hb*8192 + boff + c*512]);
      __builtin_amdgcn_s_setprio(1);
      #pragma unroll
      for (int i = 0; i < 8; i++)
        #pragma unroll
        for (int c = 0; c < 4; c++)
          acc[i][c] = __builtin_amdgcn_mfma_f32_16x16x32_bf16(af[i], bf[c], acc[i][c], 0, 0, 0);
      __builtin_amdgcn_s_setprio(0);
    }
  }
#undef STAGE8

  // epilogue
  #pragma unroll
  for (int fc = 0; fc < 4; fc++) {
    int col = col0 + wc*64 + fc*16 + l15;
    float bv = bias[col];
    #pragma unroll
    for (int fr = 0; fr < 8; fr++) {
      #pragma unroll
      for (int r = 0; r < 4; r++) {
        int row = row0 + wr*128 + fr*16 + l4*4 + r;
        float v = acc[fr][fc][r] + bv;
        if constexpr (EPI == 1) {
          float gl = 0.5f * v * (1.0f + erff(v * 0.70710678118f));
          __builtin_nontemporal_store(f2bf(gl), &Cbf[(size_t)row * M + col]);
        } else {
          int bb = row >> 10, ll = row & 1023;
          int tile = ll >> 6, kv = ll & 63;
          if (col0 < 1024) {
            __builtin_nontemporal_store(f2bf(v), &Cbf[(size_t)row * 1024 + col]);
          } else if (col0 < 2048) {
            int cc = col - 1024;
            int hh = cc >> 6, d = cc & 63;
            size_t base = (((size_t)(bb*16 + hh)*16 + tile) << 12);
            __builtin_nontemporal_store(f2bf(v), &Kt[base + kv*64 + (d ^ ((kv & 7) << 3))]);
          } else {
            int cc = col - 2048;
            int hh = cc >> 6, d = cc & 63;
            int pos = ((kv & 15) << 2) | (((kv >> 5) & 1) << 1) | ((kv >> 4) & 1);
            size_t base = (((size_t)(bb*16 + hh)*16 + tile) << 12);
            __builtin_nontemporal_store(f2bf(v), &Vt[base + d*64 + (pos ^ ((d & 7) << 3))]);
          }
        }
      }
    }
  }
}

// ---------------- 128x128 MFMA GEMM (proj / FFN2), EPI2 residual ----------------
template<int EPI>
__global__ __launch_bounds__(256) void gemm_kernel(const u16* __restrict__ A, const u16* __restrict__ W,
                                                   const float* __restrict__ bias, u16* __restrict__ Cbf,
                                                   float* __restrict__ resid,
                                                   int M, int K, int gx) {
  __shared__ u16 lsA[3][4096];
  __shared__ u16 lsB[3][4096];
  int tid = threadIdx.x;
  int lane = tid & 63;
  int w = tid >> 6;
  int wg = blockIdx.x;
  int bx = wg % gx, by = wg / gx;
  int row0 = bx << 7;
  int col0 = by << 7;
  int wr = w >> 1, wc = w & 1;

  const u16* pA[2]; const u16* pB[2];
  int dstc[2];
  #pragma unroll
  for (int i = 0; i < 2; i++) {
    int c = w * 2 + i;
    int rt = c * 16 + (lane >> 2);
    int g  = (lane & 3) ^ ((rt >> 1) & 3);
    pA[i] = A + (size_t)(row0 + rt) * K + g * 8;
    pB[i] = W + (size_t)(col0 + rt) * K + g * 8;
    dstc[i] = c * 512;
  }

  f32x4 acc[4][4] = {};
  int nt = K >> 5;

  #pragma unroll
  for (int i = 0; i < 2; i++) {
    load_lds16(pA[i], &lsA[0][dstc[i]]);
    load_lds16(pB[i], &lsB[0][dstc[i]]);
  }
  #pragma unroll
  for (int i = 0; i < 2; i++) {
    load_lds16(pA[i] + 32, &lsA[1][dstc[i]]);
    load_lds16(pB[i] + 32, &lsB[1][dstc[i]]);
  }
  asm volatile("s_waitcnt vmcnt(4)" ::: "memory");
  raw_barrier();

  int cur = 0;
  for (int t = 0; t < nt; t++) {
    int ib = (cur == 0) ? 2 : cur - 1;
    if (t + 2 < nt) {
      int kq = (t + 2) << 5;
      #pragma unroll
      for (int i = 0; i < 2; i++) {
        load_lds16(pA[i] + kq, &lsA[ib][dstc[i]]);
        load_lds16(pB[i] + kq, &lsB[ib][dstc[i]]);
      }
    }
    bf16x8 af[4], bfr[4];
    #pragma unroll
    for (int m = 0; m < 4; m++) {
      int row = wr * 64 + m * 16 + (lane & 15);
      int blk = (lane >> 4) ^ ((row >> 1) & 3);
      af[m] = *reinterpret_cast<const bf16x8*>(&lsA[cur][row * 32 + blk * 8]);
    }
    #pragma unroll
    for (int n = 0; n < 4; n++) {
      int row = wc * 64 + n * 16 + (lane & 15);
      int blk = (lane >> 4) ^ ((row >> 1) & 3);
      bfr[n] = *reinterpret_cast<const bf16x8*>(&lsB[cur][row * 32 + blk * 8]);
    }
    __builtin_amdgcn_s_setprio(1);
    #pragma unroll
    for (int m = 0; m < 4; m++)
      #pragma unroll
      for (int n = 0; n < 4; n++)
        acc[m][n] = __builtin_amdgcn_mfma_f32_16x16x32_bf16(af[m], bfr[n], acc[m][n], 0, 0, 0);
    __builtin_amdgcn_s_setprio(0);
    if (t + 2 < nt) {
      asm volatile("s_waitcnt vmcnt(4)" ::: "memory");
    } else {
      asm volatile("s_waitcnt vmcnt(0)" ::: "memory");
    }
    raw_barrier();
    cur = (cur == 2) ? 0 : cur + 1;
  }

  int rb = row0 + wr*64 + ((lane >> 4) << 2);
  int cb = col0 + wc*64 + (lane & 15);
  #pragma unroll
  for (int m = 0; m < 4; m++) {
    #pragma unroll
    for (int n = 0; n < 4; n++) {
      int col = cb + n * 16;
      float bv = bias[col];
      #pragma unroll
      for (int r = 0; r < 4; r++) {
        int row = rb + m * 16 + r;
        float v = acc[m][n][r] + bv;
        if constexpr (EPI == 0) {
          __builtin_nontemporal_store(f2bf(v), &Cbf[(size_t)row * M + col]);
        } else {
          float* p = &resid[(size_t)row * M + col];
          __builtin_nontemporal_store(*p + v, p);
        }
      }
    }
  }
}

// ---------------- flash attention, prefix-causal ----------------
__global__ __launch_bounds__(256) void attn_kernel(const u16* __restrict__ Qb,
                                                   const u16* __restrict__ Kt,
                                                   const u16* __restrict__ Vt,
                                                   u16* __restrict__ o) {
  __shared__ u16 KV[2][2][4096];
  __shared__ unsigned Ps[4][512];
  int tid = threadIdx.x;
  int lane = tid & 63;
  int wq = tid >> 6;
  int tile = blockIdx.x & 15;
  int bh = blockIdx.x >> 4;
  int b = bh >> 4;
  int h = bh & 15;
  int q0b = tile << 6;
  int q0 = q0b + wq * 16;
  size_t tok0 = (size_t)b * L_;
  int l15 = lane & 15;
  int l4  = lane >> 4;

  bf16x8 aq[2];
  #pragma unroll
  for (int kk = 0; kk < 2; kk++)
    aq[kk] = *reinterpret_cast<const bf16x8*>(Qb + (tok0 + q0 + l15) * 1024 + h * 64 + kk * 32 + (l4 << 3));

  f32x4 acc[4] = {};
  float mrow[4] = {-INFINITY, -INFINITY, -INFINITY, -INFINITY};
  float lrow[4] = {0.f, 0.f, 0.f, 0.f};
  int nkv_w = (q0b >= LS_) ? (q0 + 16) : LS_;
  bool causal = (q0b >= LS_);
  int ntiles = (q0b >= LS_) ? (tile + 1) : (LS_ >> 6);

  const u16* Kbh = Kt + (((size_t)bh) << 16);
  const u16* Vbh = Vt + (((size_t)bh) << 16);

  int soff = wq * 1024 + lane * 8;
  int doff = wq * 1024;

  #pragma unroll
  for (int i = 0; i < 2; i++) {
    load_lds16(Kbh + soff + i*512, &KV[0][0][doff + i*512]);
    load_lds16(Vbh + soff + i*512, &KV[0][1][doff + i*512]);
  }
  asm volatile("s_waitcnt vmcnt(0)" ::: "memory");
  raw_barrier();

  for (int t = 0; t < ntiles; t++) {
    int cur = t & 1;
    if (t + 1 < ntiles) {
      const u16* kn = Kbh + ((size_t)(t+1) << 12);
      const u16* vn = Vbh + ((size_t)(t+1) << 12);
      #pragma unroll
      for (int i = 0; i < 2; i++) {
        load_lds16(kn + soff + i*512, &KV[cur^1][0][doff + i*512]);
        load_lds16(vn + soff + i*512, &KV[cur^1][1][doff + i*512]);
      }
    }
    int kv0 = t << 6;
    if (kv0 < nkv_w) {
      const u16* Kl = &KV[cur][0][0];
      const u16* Vl = &KV[cur][1][0];
      f32x4 sf[4];
      __builtin_amdgcn_s_setprio(1);
      #pragma unroll
      for (int t4 = 0; t4 < 4; t4++) {
        f32x4 s = {0.f, 0.f, 0.f, 0.f};
        int kvl = t4*16 + l15;
        #pragma unroll
        for (int kk = 0; kk < 2; kk++) {
          bf16x8 bk = *reinterpret_cast<const bf16x8*>(&Kl[kvl*64 + ((kk*32 + l4*8) ^ ((l15 & 7) << 3))]);
          s = __builtin_amdgcn_mfma_f32_16x16x32_bf16(aq[kk], bk, s, 0, 0, 0);
        }
        sf[t4] = s * 0.125f;
      }
      __builtin_amdgcn_s_setprio(0);
      if (causal && (kv0 + 63 > q0)) {
        #pragma unroll
        for (int t4 = 0; t4 < 4; t4++) {
          int kvg = kv0 + t4*16 + l15;
          #pragma unroll
          for (int r = 0; r < 4; r++) {
            int qg = q0 + (l4 << 2) + r;
            if (kvg > qg) sf[t4][r] = -INFINITY;
          }
        }
      }
      float pv[4][4];
      #pragma unroll
      for (int r = 0; r < 4; r++) {
        float mx = fmaxf(fmaxf(sf[0][r], sf[1][r]), fmaxf(sf[2][r], sf[3][r]));
        #pragma unroll
        for (int off = 1; off < 16; off <<= 1) mx = fmaxf(mx, __shfl_xor(mx, off, 64));
        float mnew = fmaxf(mrow[r], mx);
        float alpha = __expf(mrow[r] - mnew);
        mrow[r] = mnew;
        float psum = 0.f;
        #pragma unroll
        for (int t4 = 0; t4 < 4; t4++) {
          float p = __expf(sf[t4][r] - mnew);
          pv[t4][r] = p;
          psum += p;
        }
        #pragma unroll
        for (int off = 1; off < 16; off <<= 1) psum += __shfl_xor(psum, off, 64);
        lrow[r] = lrow[r] * alpha + psum;
        #pragma unroll
        for (int h4 = 0; h4 < 4; h4++) acc[h4][r] *= alpha;
      }
      #pragma unroll
      for (int r = 0; r < 4; r++) {
        int ql = l4*4 + r;
        unsigned wA = (unsigned)f2bf(pv[0][r]) | ((unsigned)f2bf(pv[1][r]) << 16);
        unsigned wB = (unsigned)f2bf(pv[2][r]) | ((unsigned)f2bf(pv[3][r]) << 16);
        int xo = (ql & 7) << 2;
        Ps[wq][ql*32 + ((2*l15)     ^ xo)] = wA;
        Ps[wq][ql*32 + ((2*l15 + 1) ^ xo)] = wB;
      }
      __builtin_amdgcn_s_setprio(1);
      #pragma unroll
      for (int h4 = 0; h4 < 4; h4++) {
        int dl = h4*16 + l15;
        #pragma unroll
        for (int kk = 0; kk < 2; kk++) {
          bf16x8 pa = *reinterpret_cast<const bf16x8*>(
              (const u16*)&Ps[wq][0] + l15*64 + ((kk*32 + l4*8) ^ ((l15 & 7) << 3)));
          bf16x8 vb = *reinterpret_cast<const bf16x8*>(&Vl[dl*64 + ((kk*32 + l4*8) ^ ((l15 & 7) << 3))]);
          acc[h4] = __builtin_amdgcn_mfma_f32_16x16x32_bf16(pa, vb, acc[h4], 0, 0, 0);
        }
      }
      __builtin_amdgcn_s_setprio(0);
    }
    asm volatile("s_waitcnt vmcnt(0)" ::: "memory");
    raw_barrier();
  }
  #pragma unroll
  for (int h4 = 0; h4 < 4; h4++) {
    #pragma unroll
    for (int r = 0; r < 4; r++) {
      int row = q0 + (l4 << 2) + r;
      float ov = acc[h4][r] / lrow[r];
      o[(tok0 + row) * 1024 + h * 64 + h4*16 + l15] = f2bf(ov);
    }
  }
}

extern "C" void kernel_launch(void* const* d_in, const int* in_sizes, int n_in,
                              void* d_out, int out_size, void* d_ws, size_t ws_size,
                              hipStream_t stream) {
  (void)in_sizes; (void)n_in; (void)out_size; (void)ws_size;
  const float* sensor = (const float*)d_in[0];
  const float* traj   = (const float*)d_in[1];
  const float* pos    = (const float*)d_in[2];
  const float* ln1_s  = (const float*)d_in[3];
  const float* ln1_b  = (const float*)d_in[4];
  const float* qkv_w  = (const float*)d_in[5];
  const float* qkv_b  = (const float*)d_in[6];
  const float* out_w  = (const float*)d_in[7];
  const float* out_b  = (const float*)d_in[8];
  const float* ln2_s  = (const float*)d_in[9];
  const float* ln2_b  = (const float*)d_in[10];
  const float* w1     = (const float*)d_in[11];
  const float* b1     = (const float*)d_in[12];
  const float* w2     = (const float*)d_in[13];
  const float* b2     = (const float*)d_in[14];
  const float* fln_s  = (const float*)d_in[15];
  const float* fln_b  = (const float*)d_in[16];

  char* ws = (char*)d_ws;
  size_t off = 0;
  float* x  = (float*)(ws + off); off += (size_t)NTOK_ * D_ * 4;
  u16* h    = (u16*)(ws + off);   off += (size_t)NTOK_ * D_ * 2;
  u16* Qb   = (u16*)(ws + off);   off += (size_t)NTOK_ * D_ * 2;
  u16* Ktl  = (u16*)(ws + off);   off += (size_t)NTOK_ * D_ * 2;
  u16* Vtl  = (u16*)(ws + off);   off += (size_t)NTOK_ * D_ * 2;
  u16* ob   = (u16*)(ws + off);   off += (size_t)NTOK_ * D_ * 2;
  u16* ub   = (u16*)(ws + off);   off += (size_t)NTOK_ * FF_ * 2;
  u16* wb   = (u16*)(ws + off);   off += (size_t)FF_ * D_ * 2;

  posadd_kernel<<<NTOK_ * D_ / 1024, 256, 0, stream>>>(sensor, traj, pos, x);

  for (int i = 0; i < NL_; i++) {
    ln_kernel<u16><<<NTOK_, 256, 0, stream>>>(x, ln1_s + i*D_, ln1_b + i*D_, h);
    cast_kernel<<<(3*D_*D_/4)/256, 256, 0, stream>>>(qkv_w + (size_t)i*3*D_*D_, wb, 3*D_*D_/4);
    gemm8_kernel<3><<<32*12, 512, 0, stream>>>(h, wb, qkv_b + (size_t)i*3*D_, Qb, Ktl, Vtl, 3*D_, D_, 32);
    attn_kernel<<<B_*H_*(L_/64), 256, 0, stream>>>(Qb, Ktl, Vtl, ob);
    cast_kernel<<<(D_*D_/4)/256, 256, 0, stream>>>(out_w + (size_t)i*D_*D_, wb, D_*D_/4);
    gemm_kernel<2><<<64*8, 256, 0, stream>>>(ob, wb, out_b + (size_t)i*D_, nullptr, x, D_, D_, 64);
    ln_kernel<u16><<<NTOK_, 256, 0, stream>>>(x, ln2_s + i*D_, ln2_b + i*D_, h);
    cast_kernel<<<(FF_*D_/4)/256, 256, 0, stream>>>(w1 + (size_t)i*FF_*D_, wb, FF_*D_/4);
    gemm8_kernel<1><<<32*16, 512, 0, stream>>>(h, wb, b1 + (size_t)i*FF_, ub, nullptr, nullptr, FF_, D_, 32);
    cast_kernel<<<(FF_*D_/4)/256, 256, 0, stream>>>(w2 + (size_t)i*D_*FF_, wb, D_*FF_/4);
    gemm_kernel<2><<<64*8, 256, 0, stream>>>(ub, wb, b2 + (size_t)i*D_, nullptr, x, D_, FF_, 64);
  }
  ln_kernel<float><<<NTOK_, 256, 0, stream>>>(x, fln_s, fln_b, (float*)d_out);
}

// Round 9
// 6571.927 us; speedup vs baseline: 1.0978x; 1.0791x over previous
//
#include <hip/hip_runtime.h>
#include <cmath>

#define B_    8
#define LS_   512
#define L_    1024
#define D_    1024
#define H_    16
#define HD_   64
#define FF_   4096
#define NL_   12
#define NTOK_ (B_*L_)

typedef __attribute__((ext_vector_type(8))) short short8;
typedef __bf16 bf16x8 __attribute__((ext_vector_type(8)));
typedef __attribute__((ext_vector_type(4))) float f32x4;
typedef unsigned short u16;

__device__ __forceinline__ u16 f2bf(float f) {
  unsigned u = __builtin_bit_cast(unsigned, f);
  unsigned r = (u + 0x7fffu + ((u >> 16) & 1u)) >> 16;
  return (u16)r;
}

__device__ __forceinline__ void load_lds16(const void* g, void* l) {
  __builtin_amdgcn_global_load_lds(
      (const __attribute__((address_space(1))) unsigned*)g,
      (__attribute__((address_space(3))) unsigned*)l, 16, 0, 0);
}

__device__ __forceinline__ void raw_barrier() {
  __builtin_amdgcn_sched_barrier(0);
  __builtin_amdgcn_s_barrier();
  __builtin_amdgcn_sched_barrier(0);
}

__device__ __forceinline__ void lgkm0() {
  asm volatile("s_waitcnt lgkmcnt(0)" ::: "memory");
  __builtin_amdgcn_sched_barrier(0);
}

// ---------------- pos-embed + concat ----------------
__global__ void posadd_kernel(const float* __restrict__ sensor, const float* __restrict__ traj,
                              const float* __restrict__ pos, float* __restrict__ x) {
  int idx = blockIdx.x * blockDim.x + threadIdx.x;
  int d4 = idx & (D_/4 - 1);
  int n  = idx >> 8;
  int l  = n & (L_ - 1);
  int b  = n >> 10;
  const float* src = (l < LS_) ? (sensor + ((size_t)(b*LS_ + l))*D_)
                               : (traj   + ((size_t)(b*LS_ + l - LS_))*D_);
  float4 v = reinterpret_cast<const float4*>(src)[d4];
  float4 p = reinterpret_cast<const float4*>(pos + (size_t)l*D_)[d4];
  v.x += p.x; v.y += p.y; v.z += p.z; v.w += p.w;
  reinterpret_cast<float4*>(x + (size_t)n*D_)[d4] = v;
}

// ---------------- LayerNorm ----------------
template<typename OUT>
__global__ __launch_bounds__(256) void ln_kernel(const float* __restrict__ x,
                                                 const float* __restrict__ gam,
                                                 const float* __restrict__ bet,
                                                 OUT* __restrict__ out) {
  int row = blockIdx.x;
  int t = threadIdx.x;
  float4 v = reinterpret_cast<const float4*>(x + (size_t)row * D_)[t];
  float sum = v.x + v.y + v.z + v.w;
  float sq  = v.x*v.x + v.y*v.y + v.z*v.z + v.w*v.w;
  #pragma unroll
  for (int o = 1; o < 64; o <<= 1) {
    sum += __shfl_xor(sum, o, 64);
    sq  += __shfl_xor(sq,  o, 64);
  }
  __shared__ float ps[4], pq[4];
  int w = t >> 6;
  if ((t & 63) == 0) { ps[w] = sum; pq[w] = sq; }
  __syncthreads();
  sum = ps[0] + ps[1] + ps[2] + ps[3];
  sq  = pq[0] + pq[1] + pq[2] + pq[3];
  float mean = sum * (1.0f / D_);
  float var  = sq  * (1.0f / D_) - mean * mean;
  float inv  = rsqrtf(var + 1e-5f);
  float4 g  = reinterpret_cast<const float4*>(gam)[t];
  float4 bb = reinterpret_cast<const float4*>(bet)[t];
  float o0 = (v.x - mean) * inv * g.x + bb.x;
  float o1 = (v.y - mean) * inv * g.y + bb.y;
  float o2 = (v.z - mean) * inv * g.z + bb.z;
  float o3 = (v.w - mean) * inv * g.w + bb.w;
  if constexpr (sizeof(OUT) == 2) {
    ushort4 r; r.x = f2bf(o0); r.y = f2bf(o1); r.z = f2bf(o2); r.w = f2bf(o3);
    reinterpret_cast<ushort4*>(out + (size_t)row * D_)[t] = r;
  } else {
    float4 r; r.x = o0; r.y = o1; r.z = o2; r.w = o3;
    reinterpret_cast<float4*>(out + (size_t)row * D_)[t] = r;
  }
}

// ---------------- fp32 -> bf16 cast ----------------
__global__ void cast_kernel(const float* __restrict__ in, u16* __restrict__ out, int n4) {
  int i = blockIdx.x * blockDim.x + threadIdx.x;
  if (i >= n4) return;
  float4 v = reinterpret_cast<const float4*>(in)[i];
  ushort4 r; r.x = f2bf(v.x); r.y = f2bf(v.y); r.z = f2bf(v.z); r.w = f2bf(v.w);
  reinterpret_cast<ushort4*>(out)[i] = r;
}

// ============ 256x256 GEMM, faithful m201 8-phase schedule ============
// 512 thr = 8 waves (2M x 4N); per-wave out 128x64; BK=64; 2 K-tiles/iter.
// LDS: 8 half-buffers [128][64] u16 (16KB each) = 128KB.
//   index: ls[(tile&1)<<2 | op<<1 | half], op 0=A 1=B.
// Swizzle: 16B-granule g (0..7 per 128B row) stored at g ^ ((row>>1)&7);
//   since rows differ by multiples of 16 within frags, mask = (l15>>1).
// Staging: phase p stages ONE half-tile (2 gload_lds/wave), slot order
//   ph0:T1.A1 ph1:T1.B0 ph2:T1.B1 ph3:T2.A0 ph4:T2.A1 ph5:T2.B0 ph6:T2.B1 ph7:T3.A0
// vmcnt(4) only at ph0/ph4 (confirms incoming K-tile, leaves 2 halves in flight).
template<int EPI>
__global__ __launch_bounds__(512) void gemm256_kernel(const u16* __restrict__ A, const u16* __restrict__ W,
                                                      const float* __restrict__ bias, u16* __restrict__ Cbf,
                                                      u16* __restrict__ Kt, u16* __restrict__ Vt,
                                                      int M, int K, int gx) {
  __shared__ u16 ls[8][8192];
  int tid = threadIdx.x, lane = tid & 63, w = tid >> 6;
  int wr = w >> 2, wc = w & 3;
  int bid = blockIdx.x, bx = bid % gx, by = bid / gx;
  int row0 = bx << 8, col0 = by << 8;
  int l15 = lane & 15, l4 = lane >> 4;
  int msk = l15 >> 1;
  int aoff0 = l15*64 + ((l4 ^ msk) << 3);
  int aoff1 = l15*64 + (((4 + l4) ^ msk) << 3);

  // staging addresses (inverse-swizzled global source, linear LDS dest)
  int c0 = w*2, c1 = w*2 + 1;
  int rIn0 = c0*8 + (lane >> 3), rIn1 = c1*8 + (lane >> 3);
  int gs0 = (lane & 7) ^ (lane >> 4);        // c0 even
  int gs1 = (lane & 7) ^ (4 | (lane >> 4));  // c1 odd
  const u16* sA0 = A + (size_t)(row0 + rIn0)*K + gs0*8;
  const u16* sA1 = A + (size_t)(row0 + rIn1)*K + gs1*8;
  const u16* sB0 = W + (size_t)(col0 + rIn0)*K + gs0*8;
  const u16* sB1 = W + (size_t)(col0 + rIn1)*K + gs1*8;
  size_t hK = (size_t)128 * K;
  int nt = K >> 6;

#define STG(op, tile, half) do { if ((tile) < nt) { \
    int _b = (((tile)&1)<<2) | ((op)<<1) | (half); \
    size_t _o = (size_t)(half)*hK + (size_t)(tile)*64; \
    if (op) { load_lds16(sB0 + _o, &ls[_b][c0*512]); load_lds16(sB1 + _o, &ls[_b][c1*512]); } \
    else    { load_lds16(sA0 + _o, &ls[_b][c0*512]); load_lds16(sA1 + _o, &ls[_b][c1*512]); } \
  } } while (0)

  f32x4 acc[8][4] = {};
  bf16x8 af[4][2], bfr[2][2][2];
  const u16* lA[2] = { &ls[wr][0],                    &ls[4 | wr][0] };
  const u16* lB[2] = { &ls[2 | (wc >> 1)][(wc & 1) * 4096], &ls[6 | (wc >> 1)][(wc & 1) * 4096] };

#define RDA(buf, mh) do { _Pragma("unroll") for (int i = 0; i < 4; i++) { \
    af[i][0] = *reinterpret_cast<const bf16x8*>(&lA[buf][(mh)*4096 + i*1024 + aoff0]); \
    af[i][1] = *reinterpret_cast<const bf16x8*>(&lA[buf][(mh)*4096 + i*1024 + aoff1]); } } while (0)
#define RDB(buf, nh) do { _Pragma("unroll") for (int c = 0; c < 2; c++) { \
    bfr[nh][c][0] = *reinterpret_cast<const bf16x8*>(&lB[buf][((nh)*2+c)*1024 + aoff0]); \
    bfr[nh][c][1] = *reinterpret_cast<const bf16x8*>(&lB[buf][((nh)*2+c)*1024 + aoff1]); } } while (0)
#define MM(mh, nh) do { __builtin_amdgcn_s_setprio(1); \
    _Pragma("unroll") for (int i = 0; i < 4; i++) \
    _Pragma("unroll") for (int c = 0; c < 2; c++) \
    _Pragma("unroll") for (int ks = 0; ks < 2; ks++) \
      acc[(mh)*4+i][(nh)*2+c] = __builtin_amdgcn_mfma_f32_16x16x32_bf16(af[i][ks], bfr[nh][c][ks], acc[(mh)*4+i][(nh)*2+c], 0, 0, 0); \
    __builtin_amdgcn_s_setprio(0); } while (0)

  // prologue: T0 complete + T1.A0 (10 loads in flight)
  STG(0,0,0); STG(0,0,1); STG(1,0,0); STG(1,0,1);
  STG(0,1,0);

  int ni = nt >> 1;
  for (int it = 0; it < ni; it++) {
    int T1 = it*2 + 1, T2 = it*2 + 2, T3 = it*2 + 3;
    bool lastit = (it == ni - 1);
    // ---- ph0 (buf0: mh0,nh0) ----
    STG(0, T1, 1);
    asm volatile("s_waitcnt vmcnt(4)" ::: "memory");
    raw_barrier();
    RDA(0,0); RDB(0,0);
    lgkm0();
    MM(0,0);
    raw_barrier();
    // ---- ph1 (buf0: mh0,nh1) ----
    RDB(0,1);
    STG(1, T1, 0);
    raw_barrier(); lgkm0(); MM(0,1); raw_barrier();
    // ---- ph2 (buf0: mh1,nh0) ----
    RDA(0,1);
    STG(1, T1, 1);
    raw_barrier(); lgkm0(); MM(1,0); raw_barrier();
    // ---- ph3 (buf0: mh1,nh1) ----
    STG(0, T2, 0);
    raw_barrier(); MM(1,1); raw_barrier();
    // ---- ph4 (buf1: mh0,nh0) ----
    STG(0, T2, 1);
    if (lastit) asm volatile("s_waitcnt vmcnt(0)" ::: "memory");
    else        asm volatile("s_waitcnt vmcnt(4)" ::: "memory");
    raw_barrier();
    RDA(1,0); RDB(1,0);
    lgkm0();
    MM(0,0);
    raw_barrier();
    // ---- ph5 (buf1: mh0,nh1) ----
    RDB(1,1);
    STG(1, T2, 0);
    raw_barrier(); lgkm0(); MM(0,1); raw_barrier();
    // ---- ph6 (buf1: mh1,nh0) ----
    RDA(1,1);
    STG(1, T2, 1);
    raw_barrier(); lgkm0(); MM(1,0); raw_barrier();
    // ---- ph7 (buf1: mh1,nh1) ----
    STG(0, T3, 0);
    raw_barrier(); MM(1,1); raw_barrier();
  }
#undef STG
#undef RDA
#undef RDB
#undef MM

  // epilogue
  #pragma unroll
  for (int fc = 0; fc < 4; fc++) {
    int col = col0 + wc*64 + fc*16 + l15;
    float bv = bias[col];
    #pragma unroll
    for (int fr = 0; fr < 8; fr++) {
      #pragma unroll
      for (int r = 0; r < 4; r++) {
        int row = row0 + wr*128 + fr*16 + l4*4 + r;
        float v = acc[fr][fc][r] + bv;
        if constexpr (EPI == 1) {
          float gl = 0.5f * v * (1.0f + erff(v * 0.70710678118f));
          Cbf[(size_t)row * M + col] = f2bf(gl);
        } else {
          int bb = row >> 10, ll = row & 1023;
          int tile = ll >> 6, kv = ll & 63;
          if (col0 < 1024) {
            Cbf[(size_t)row * 1024 + col] = f2bf(v);
          } else if (col0 < 2048) {
            int cc = col - 1024;
            int hh = cc >> 6, d = cc & 63;
            size_t base = (((size_t)(bb*16 + hh)*16 + tile) << 12);
            Kt[base + kv*64 + (d ^ ((kv & 7) << 3))] = f2bf(v);
          } else {
            int cc = col - 2048;
            int hh = cc >> 6, d = cc & 63;
            int pos = ((kv & 15) << 2) | (((kv >> 5) & 1) << 1) | ((kv >> 4) & 1);
            size_t base = (((size_t)(bb*16 + hh)*16 + tile) << 12);
            Vt[base + d*64 + (pos ^ ((d & 7) << 3))] = f2bf(v);
          }
        }
      }
    }
  }
}

// ---------------- 128x128 MFMA GEMM (proj / FFN2), 3-buf depth-2 ----------------
template<int EPI>
__global__ __launch_bounds__(256) void gemm_kernel(const u16* __restrict__ A, const u16* __restrict__ W,
                                                   const float* __restrict__ bias, u16* __restrict__ Cbf,
                                                   float* __restrict__ resid,
                                                   int M, int K, int gx) {
  __shared__ u16 lsA[3][4096];
  __shared__ u16 lsB[3][4096];
  int tid = threadIdx.x;
  int lane = tid & 63;
  int w = tid >> 6;
  int wg = blockIdx.x;
  int bx = wg % gx, by = wg / gx;
  int row0 = bx << 7;
  int col0 = by << 7;
  int wr = w >> 1, wc = w & 1;

  const u16* pA[2]; const u16* pB[2];
  int dstc[2];
  #pragma unroll
  for (int i = 0; i < 2; i++) {
    int c = w * 2 + i;
    int rt = c * 16 + (lane >> 2);
    int g  = (lane & 3) ^ ((rt >> 1) & 3);
    pA[i] = A + (size_t)(row0 + rt) * K + g * 8;
    pB[i] = W + (size_t)(col0 + rt) * K + g * 8;
    dstc[i] = c * 512;
  }

  f32x4 acc[4][4] = {};
  int nt = K >> 5;

  #pragma unroll
  for (int i = 0; i < 2; i++) {
    load_lds16(pA[i], &lsA[0][dstc[i]]);
    load_lds16(pB[i], &lsB[0][dstc[i]]);
  }
  #pragma unroll
  for (int i = 0; i < 2; i++) {
    load_lds16(pA[i] + 32, &lsA[1][dstc[i]]);
    load_lds16(pB[i] + 32, &lsB[1][dstc[i]]);
  }
  asm volatile("s_waitcnt vmcnt(4)" ::: "memory");
  raw_barrier();

  int cur = 0;
  for (int t = 0; t < nt; t++) {
    int ib = (cur == 0) ? 2 : cur - 1;
    if (t + 2 < nt) {
      int kq = (t + 2) << 5;
      #pragma unroll
      for (int i = 0; i < 2; i++) {
        load_lds16(pA[i] + kq, &lsA[ib][dstc[i]]);
        load_lds16(pB[i] + kq, &lsB[ib][dstc[i]]);
      }
    }
    bf16x8 af[4], bfr[4];
    #pragma unroll
    for (int m = 0; m < 4; m++) {
      int row = wr * 64 + m * 16 + (lane & 15);
      int blk = (lane >> 4) ^ ((row >> 1) & 3);
      af[m] = *reinterpret_cast<const bf16x8*>(&lsA[cur][row * 32 + blk * 8]);
    }
    #pragma unroll
    for (int n = 0; n < 4; n++) {
      int row = wc * 64 + n * 16 + (lane & 15);
      int blk = (lane >> 4) ^ ((row >> 1) & 3);
      bfr[n] = *reinterpret_cast<const bf16x8*>(&lsB[cur][row * 32 + blk * 8]);
    }
    __builtin_amdgcn_s_setprio(1);
    #pragma unroll
    for (int m = 0; m < 4; m++)
      #pragma unroll
      for (int n = 0; n < 4; n++)
        acc[m][n] = __builtin_amdgcn_mfma_f32_16x16x32_bf16(af[m], bfr[n], acc[m][n], 0, 0, 0);
    __builtin_amdgcn_s_setprio(0);
    if (t + 2 < nt) {
      asm volatile("s_waitcnt vmcnt(4)" ::: "memory");
    } else {
      asm volatile("s_waitcnt vmcnt(0)" ::: "memory");
    }
    raw_barrier();
    cur = (cur == 2) ? 0 : cur + 1;
  }

  int rb = row0 + wr*64 + ((lane >> 4) << 2);
  int cb = col0 + wc*64 + (lane & 15);
  #pragma unroll
  for (int m = 0; m < 4; m++) {
    #pragma unroll
    for (int n = 0; n < 4; n++) {
      int col = cb + n * 16;
      float bv = bias[col];
      #pragma unroll
      for (int r = 0; r < 4; r++) {
        int row = rb + m * 16 + r;
        float v = acc[m][n][r] + bv;
        if constexpr (EPI == 0) {
          Cbf[(size_t)row * M + col] = f2bf(v);
        } else {
          resid[(size_t)row * M + col] += v;
        }
      }
    }
  }
}

// ---------------- flash attention, prefix-causal ----------------
__global__ __launch_bounds__(256) void attn_kernel(const u16* __restrict__ Qb,
                                                   const u16* __restrict__ Kt,
                                                   const u16* __restrict__ Vt,
                                                   u16* __restrict__ o) {
  __shared__ u16 KV[2][2][4096];
  __shared__ unsigned Ps[4][512];
  int tid = threadIdx.x;
  int lane = tid & 63;
  int wq = tid >> 6;
  int tile = blockIdx.x & 15;
  int bh = blockIdx.x >> 4;
  int b = bh >> 4;
  int h = bh & 15;
  int q0b = tile << 6;
  int q0 = q0b + wq * 16;
  size_t tok0 = (size_t)b * L_;
  int l15 = lane & 15;
  int l4  = lane >> 4;

  bf16x8 aq[2];
  #pragma unroll
  for (int kk = 0; kk < 2; kk++)
    aq[kk] = *reinterpret_cast<const bf16x8*>(Qb + (tok0 + q0 + l15) * 1024 + h * 64 + kk * 32 + (l4 << 3));

  f32x4 acc[4] = {};
  float mrow[4] = {-INFINITY, -INFINITY, -INFINITY, -INFINITY};
  float lrow[4] = {0.f, 0.f, 0.f, 0.f};
  int nkv_w = (q0b >= LS_) ? (q0 + 16) : LS_;
  bool causal = (q0b >= LS_);
  int ntiles = (q0b >= LS_) ? (tile + 1) : (LS_ >> 6);

  const u16* Kbh = Kt + (((size_t)bh) << 16);
  const u16* Vbh = Vt + (((size_t)bh) << 16);

  int soff = wq * 1024 + lane * 8;
  int doff = wq * 1024;

  #pragma unroll
  for (int i = 0; i < 2; i++) {
    load_lds16(Kbh + soff + i*512, &KV[0][0][doff + i*512]);
    load_lds16(Vbh + soff + i*512, &KV[0][1][doff + i*512]);
  }
  asm volatile("s_waitcnt vmcnt(0)" ::: "memory");
  raw_barrier();

  for (int t = 0; t < ntiles; t++) {
    int cur = t & 1;
    if (t + 1 < ntiles) {
      const u16* kn = Kbh + ((size_t)(t+1) << 12);
      const u16* vn = Vbh + ((size_t)(t+1) << 12);
      #pragma unroll
      for (int i = 0; i < 2; i++) {
        load_lds16(kn + soff + i*512, &KV[cur^1][0][doff + i*512]);
        load_lds16(vn + soff + i*512, &KV[cur^1][1][doff + i*512]);
      }
    }
    int kv0 = t << 6;
    if (kv0 < nkv_w) {
      const u16* Kl = &KV[cur][0][0];
      const u16* Vl = &KV[cur][1][0];
      f32x4 sf[4];
      __builtin_amdgcn_s_setprio(1);
      #pragma unroll
      for (int t4 = 0; t4 < 4; t4++) {
        f32x4 s = {0.f, 0.f, 0.f, 0.f};
        int kvl = t4*16 + l15;
        #pragma unroll
        for (int kk = 0; kk < 2; kk++) {
          bf16x8 bk = *reinterpret_cast<const bf16x8*>(&Kl[kvl*64 + ((kk*32 + l4*8) ^ ((l15 & 7) << 3))]);
          s = __builtin_amdgcn_mfma_f32_16x16x32_bf16(aq[kk], bk, s, 0, 0, 0);
        }
        sf[t4] = s * 0.125f;
      }
      __builtin_amdgcn_s_setprio(0);
      if (causal && (kv0 + 63 > q0)) {
        #pragma unroll
        for (int t4 = 0; t4 < 4; t4++) {
          int kvg = kv0 + t4*16 + l15;
          #pragma unroll
          for (int r = 0; r < 4; r++) {
            int qg = q0 + (l4 << 2) + r;
            if (kvg > qg) sf[t4][r] = -INFINITY;
          }
        }
      }
      float pv[4][4];
      #pragma unroll
      for (int r = 0; r < 4; r++) {
        float mx = fmaxf(fmaxf(sf[0][r], sf[1][r]), fmaxf(sf[2][r], sf[3][r]));
        #pragma unroll
        for (int off = 1; off < 16; off <<= 1) mx = fmaxf(mx, __shfl_xor(mx, off, 64));
        float mnew = fmaxf(mrow[r], mx);
        float alpha = __expf(mrow[r] - mnew);
        mrow[r] = mnew;
        float psum = 0.f;
        #pragma unroll
        for (int t4 = 0; t4 < 4; t4++) {
          float p = __expf(sf[t4][r] - mnew);
          pv[t4][r] = p;
          psum += p;
        }
        #pragma unroll
        for (int off = 1; off < 16; off <<= 1) psum += __shfl_xor(psum, off, 64);
        lrow[r] = lrow[r] * alpha + psum;
        #pragma unroll
        for (int h4 = 0; h4 < 4; h4++) acc[h4][r] *= alpha;
      }
      #pragma unroll
      for (int r = 0; r < 4; r++) {
        int ql = l4*4 + r;
        unsigned wA = (unsigned)f2bf(pv[0][r]) | ((unsigned)f2bf(pv[1][r]) << 16);
        unsigned wB = (unsigned)f2bf(pv[2][r]) | ((unsigned)f2bf(pv[3][r]) << 16);
        int xo = (ql & 7) << 2;
        Ps[wq][ql*32 + ((2*l15)     ^ xo)] = wA;
        Ps[wq][ql*32 + ((2*l15 + 1) ^ xo)] = wB;
      }
      __builtin_amdgcn_s_setprio(1);
      #pragma unroll
      for (int h4 = 0; h4 < 4; h4++) {
        int dl = h4*16 + l15;
        #pragma unroll
        for (int kk = 0; kk < 2; kk++) {
          bf16x8 pa = *reinterpret_cast<const bf16x8*>(
              (const u16*)&Ps[wq][0] + l15*64 + ((kk*32 + l4*8) ^ ((l15 & 7) << 3)));
          bf16x8 vb = *reinterpret_cast<const bf16x8*>(&Vl[dl*64 + ((kk*32 + l4*8) ^ ((l15 & 7) << 3))]);
          acc[h4] = __builtin_amdgcn_mfma_f32_16x16x32_bf16(pa, vb, acc[h4], 0, 0, 0);
        }
      }
      __builtin_amdgcn_s_setprio(0);
    }
    asm volatile("s_waitcnt vmcnt(0)" ::: "memory");
    raw_barrier();
  }
  #pragma unroll
  for (int h4 = 0; h4 < 4; h4++) {
    #pragma unroll
    for (int r = 0; r < 4; r++) {
      int row = q0 + (l4 << 2) + r;
      float ov = acc[h4][r] / lrow[r];
      o[(tok0 + row) * 1024 + h * 64 + h4*16 + l15] = f2bf(ov);
    }
  }
}

extern "C" void kernel_launch(void* const* d_in, const int* in_sizes, int n_in,
                              void* d_out, int out_size, void* d_ws, size_t ws_size,
                              hipStream_t stream) {
  (void)in_sizes; (void)n_in; (void)out_size; (void)ws_size;
  const float* sensor = (const float*)d_in[0];
  const float* traj   = (const float*)d_in[1];
  const float* pos    = (const float*)d_in[2];
  const float* ln1_s  = (const float*)d_in[3];
  const float* ln1_b  = (const float*)d_in[4];
  const float* qkv_w  = (const float*)d_in[5];
  const float* qkv_b  = (const float*)d_in[6];
  const float* out_w  = (const float*)d_in[7];
  const float* out_b  = (const float*)d_in[8];
  const float* ln2_s  = (const float*)d_in[9];
  const float* ln2_b  = (const float*)d_in[10];
  const float* w1     = (const float*)d_in[11];
  const float* b1     = (const float*)d_in[12];
  const float* w2     = (const float*)d_in[13];
  const float* b2     = (const float*)d_in[14];
  const float* fln_s  = (const float*)d_in[15];
  const float* fln_b  = (const float*)d_in[16];

  char* ws = (char*)d_ws;
  size_t off = 0;
  float* x  = (float*)(ws + off); off += (size_t)NTOK_ * D_ * 4;
  u16* h    = (u16*)(ws + off);   off += (size_t)NTOK_ * D_ * 2;
  u16* Qb   = (u16*)(ws + off);   off += (size_t)NTOK_ * D_ * 2;
  u16* Ktl  = (u16*)(ws + off);   off += (size_t)NTOK_ * D_ * 2;
  u16* Vtl  = (u16*)(ws + off);   off += (size_t)NTOK_ * D_ * 2;
  u16* ob   = (u16*)(ws + off);   off += (size_t)NTOK_ * D_ * 2;
  u16* ub   = (u16*)(ws + off);   off += (size_t)NTOK_ * FF_ * 2;
  u16* wb   = (u16*)(ws + off);   off += (size_t)FF_ * D_ * 2;

  posadd_kernel<<<NTOK_ * D_ / 1024, 256, 0, stream>>>(sensor, traj, pos, x);

  for (int i = 0; i < NL_; i++) {
    ln_kernel<u16><<<NTOK_, 256, 0, stream>>>(x, ln1_s + i*D_, ln1_b + i*D_, h);
    cast_kernel<<<(3*D_*D_/4)/256, 256, 0, stream>>>(qkv_w + (size_t)i*3*D_*D_, wb, 3*D_*D_/4);
    gemm256_kernel<3><<<32*12, 512, 0, stream>>>(h, wb, qkv_b + (size_t)i*3*D_, Qb, Ktl, Vtl, 3*D_, D_, 32);
    attn_kernel<<<B_*H_*(L_/64), 256, 0, stream>>>(Qb, Ktl, Vtl, ob);
    cast_kernel<<<(D_*D_/4)/256, 256, 0, stream>>>(out_w + (size_t)i*D_*D_, wb, D_*D_/4);
    gemm_kernel<2><<<64*8, 256, 0, stream>>>(ob, wb, out_b + (size_t)i*D_, nullptr, x, D_, D_, 64);
    ln_kernel<u16><<<NTOK_, 256, 0, stream>>>(x, ln2_s + i*D_, ln2_b + i*D_, h);
    cast_kernel<<<(FF_*D_/4)/256, 256, 0, stream>>>(w1 + (size_t)i*FF_*D_, wb, FF_*D_/4);
    gemm256_kernel<1><<<32*16, 512, 0, stream>>>(h, wb, b1 + (size_t)i*FF_, ub, nullptr, nullptr, FF_, D_, 32);
    cast_kernel<<<(FF_*D_/4)/256, 256, 0, stream>>>(w2 + (size_t)i*D_*FF_, wb, D_*FF_/4);
    gemm_kernel<2><<<64*8, 256, 0, stream>>>(ub, wb, b2 + (size_t)i*D_, nullptr, x, D_, FF_, 64);
  }
  ln_kernel<float><<<NTOK_, 256, 0, stream>>>(x, fln_s, fln_b, (float*)d_out);
}